// Round 1
// baseline (3025.868 us; speedup 1.0000x reference)
//
#include <hip/hip_runtime.h>
#include <stdint.h>

// ============================================================================
// GRU_Model: 2-layer bidirectional GRU, B=512 T=64 E=300 H=512, fp16 MFMA.
//
// All tensors that feed MFMA live in "fragment layout":
//   A/B-operand frag unit (16 rows x 32 k): [unit][lane64][8 halves], where
//   lane l holds row (l&15), k = (l>>4)*8 + j.  (16x16x32_f16 operand layout)
//   C/D: lane l, reg r holds D[row=(l>>4)*4+r][col=l&15]  (m89-verified).
// gx is stored in C-frag tile layout [mtile16][ntile16][256] so the GEMM
// epilogue writes coalesced 8B and the scan reads the same positions.
//
// Scan: persistent kernel, 256 blocks = dir(2) x mtile64(8) x hcolslice32(16).
// Whh slice (3 gates x 32 cols x K=512 = 48 frags) cached in VGPRs.
// Per-group (d,mtile) monotonic-counter barrier, parity double-buffered h.
// ============================================================================

#define NTW 192   // 3072/16 gate-column tiles (both dirs)
#define MTX 2048  // 32768/16 row tiles (B*T)

typedef _Float16 half8 __attribute__((ext_vector_type(8)));
typedef _Float16 half4_t __attribute__((ext_vector_type(4)));
typedef float float4_t __attribute__((ext_vector_type(4)));

__device__ __forceinline__ void gl_lds16(const void* g, void* l) {
  __builtin_amdgcn_global_load_lds(
      (const __attribute__((address_space(1))) void*)g,
      (__attribute__((address_space(3))) void*)l, 16, 0, 0);
}

__device__ __forceinline__ float sigm_f(float x) { return 1.f / (1.f + __expf(-x)); }
__device__ __forceinline__ float tanh_f(float x) { return 1.f - 2.f / (__expf(2.f * x) + 1.f); }

// f32 (3072, K) row-major -> fp16 frag layout [192][KI][64][8], zero-pad to KI*32
__global__ void pack_b_kernel(const float* __restrict__ src, _Float16* __restrict__ dst,
                              int K, int KI) {
  int gid = blockIdx.x * 256 + threadIdx.x;
  int l = gid & 63, unit = gid >> 6;
  int nt = unit / KI, ks = unit - nt * KI;
  if (nt >= NTW) return;
  int row = nt * 16 + (l & 15);
  int col0 = ks * 32 + ((l >> 4) << 3);
  half8 v;
#pragma unroll
  for (int j = 0; j < 8; ++j) {
    int c = col0 + j;
    v[j] = (c < K) ? (_Float16)src[(long)row * K + c] : (_Float16)0.f;
  }
  *(half8*)(dst + (long)unit * 512 + l * 8) = v;
}

// embedding gather -> x0 frag layout [2048][10][64][8] (K=300 padded to 320)
__global__ void gather_kernel(const int* __restrict__ tokens, const float* __restrict__ emb,
                              _Float16* __restrict__ x0) {
  int gid = blockIdx.x * 256 + threadIdx.x;
  int l = gid & 63, unit = gid >> 6;
  int mt = unit / 10, ks = unit - mt * 10;
  if (mt >= MTX) return;
  int row = mt * 16 + (l & 15);  // row = b*64 + t
  const float* e = emb + (long)tokens[row] * 300;
  int col0 = ks * 32 + ((l >> 4) << 3);
  half8 v;
#pragma unroll
  for (int j = 0; j < 8; ++j) {
    int c = col0 + j;
    v[j] = (c < 300) ? (_Float16)e[c] : (_Float16)0.f;
  }
  *(half8*)(x0 + (long)unit * 512 + l * 8) = v;
}

// C(M=32768,N=3072) = A(M,K) * B(N,K)^T + bias[n];  A,B frag-layout fp16,
// C in C-frag tile layout [mtile][ntile][256] fp16.  grid (24, 256), 256 thr.
__global__ __launch_bounds__(256) void gemm_bt_kernel(
    const _Float16* __restrict__ A, const _Float16* __restrict__ Bw,
    const float* __restrict__ bias, _Float16* __restrict__ C, int KI) {
  __shared__ _Float16 As[8 * 512];
  __shared__ _Float16 Bs[8 * 512];
  const int bx = blockIdx.x, by = blockIdx.y;
  const int tid = threadIdx.x, w = tid >> 6, l = tid & 63;
  const int wm = w >> 1, wn = w & 1, ln = l & 15;
  const int mt0 = by * 8, nt0 = bx * 8;
  float4_t acc[4][4];
#pragma unroll
  for (int i = 0; i < 4; ++i)
#pragma unroll
    for (int j = 0; j < 4; ++j) acc[i][j] = 0.f;
  for (int it = 0; it < KI; ++it) {
    __syncthreads();  // protect LDS from previous iter's readers
    gl_lds16(A + ((long)(mt0 + w) * KI + it) * 512 + l * 8, As + w * 512 + l * 8);
    gl_lds16(A + ((long)(mt0 + w + 4) * KI + it) * 512 + l * 8, As + (w + 4) * 512 + l * 8);
    gl_lds16(Bw + ((long)(nt0 + w) * KI + it) * 512 + l * 8, Bs + w * 512 + l * 8);
    gl_lds16(Bw + ((long)(nt0 + w + 4) * KI + it) * 512 + l * 8, Bs + (w + 4) * 512 + l * 8);
    __syncthreads();  // compiler emits vmcnt(0) drain
    half8 af[4], bf[4];
#pragma unroll
    for (int i = 0; i < 4; ++i) af[i] = *(const half8*)(As + (wm * 4 + i) * 512 + l * 8);
#pragma unroll
    for (int j = 0; j < 4; ++j) bf[j] = *(const half8*)(Bs + (wn * 4 + j) * 512 + l * 8);
#pragma unroll
    for (int i = 0; i < 4; ++i)
#pragma unroll
      for (int j = 0; j < 4; ++j)
        acc[i][j] = __builtin_amdgcn_mfma_f32_16x16x32_f16(af[i], bf[j], acc[i][j], 0, 0, 0);
  }
#pragma unroll
  for (int i = 0; i < 4; ++i)
#pragma unroll
    for (int j = 0; j < 4; ++j) {
      int mt = mt0 + wm * 4 + i, ntile = nt0 + wn * 4 + j;
      float bv = bias[ntile * 16 + ln];
      half4_t o;
#pragma unroll
      for (int r = 0; r < 4; ++r) o[r] = (_Float16)(acc[i][j][r] + bv);
      *(half4_t*)(C + ((long)mt * NTW + ntile) * 256 + l * 4) = o;  // coalesced 8B
    }
}

// Persistent bidirectional GRU scan over 64 steps.
// grid 256 = d(2) x mtb(8: 64 batch rows) x nt(16: 32 h-cols). 256 thr.
// hbuf: [d*2+parity][32 mtiles][16 ks][64][8] fp16 (frag layout, 512KB/slot).
__global__ __launch_bounds__(256, 1) void gru_scan_kernel(
    const _Float16* __restrict__ whh,  // [192][16][64][8]
    const float* __restrict__ bhh,     // [3072]
    const _Float16* __restrict__ gx,   // [2048][192][256] (C-frag tiles)
    _Float16* hbuf, _Float16* ys,      // ys: x1 frag [2048][32][64][8] or null
    float* last,                       // [512][1024] f32 or null
    unsigned int* cnt) {               // 16 group counters, 128B stride
  const int bid = blockIdx.x;
  const int d = bid >> 7, mtb = (bid >> 4) & 7, nt = bid & 15;
  const int tid = threadIdx.x, w = tid >> 6, l = tid & 63;
  const int wm = w >> 1, wn = w & 1, lq = l >> 4, ln = l & 15;
  unsigned int* gc = cnt + (d * 8 + mtb) * 32;
  const int hcol = nt * 32 + wn * 16 + ln;  // this lane's h column

  // Whh slice resident in VGPRs for all 64 steps (48 frags = 192 VGPRs)
  half8 bf[3][16];
#pragma unroll
  for (int g = 0; g < 3; ++g) {
    const int tg = d * 96 + g * 32 + nt * 2 + wn;
#pragma unroll
    for (int ks = 0; ks < 16; ++ks)
      bf[g][ks] = *(const half8*)(whh + (long)(tg * 16 + ks) * 512 + l * 8);
  }
  const float bh0 = bhh[d * 1536 + hcol];
  const float bh1 = bhh[d * 1536 + 512 + hcol];
  const float bh2 = bhh[d * 1536 + 1024 + hcol];
  float hreg[2][4] = {{0.f, 0.f, 0.f, 0.f}, {0.f, 0.f, 0.f, 0.f}};  // fp32 master h
  const int mtr0 = mtb * 4 + wm * 2;  // global h row-tile for i=0
  const int ksh = nt, qh = (hcol >> 3) & 3, jh = hcol & 7;
  const int ntg0 = d * 96 + nt * 2 + wn;

  for (int s = 0; s < 64; ++s) {
    const int par = s & 1;
    const _Float16* hrd = hbuf + (long)(d * 2 + par) * 262144;
    _Float16* hwr = hbuf + (long)(d * 2 + (par ^ 1)) * 262144;
    float4_t acc[3][2];
#pragma unroll
    for (int g = 0; g < 3; ++g) { acc[g][0] = 0.f; acc[g][1] = 0.f; }
#pragma unroll
    for (int kk = 0; kk < 2; ++kk) {  // 2 chunks of 8 k-steps caps af VGPRs
      half8 af[2][8];
#pragma unroll
      for (int i = 0; i < 2; ++i)
#pragma unroll
        for (int k2 = 0; k2 < 8; ++k2)
          af[i][k2] = *(const half8*)(hrd + ((long)(mtr0 + i) * 16 + kk * 8 + k2) * 512 + l * 8);
#pragma unroll
      for (int k2 = 0; k2 < 8; ++k2)
#pragma unroll
        for (int i = 0; i < 2; ++i)
#pragma unroll
          for (int g = 0; g < 3; ++g)
            acc[g][i] = __builtin_amdgcn_mfma_f32_16x16x32_f16(af[i][k2], bf[g][kk * 8 + k2],
                                                               acc[g][i], 0, 0, 0);
    }
    const int t_in = d ? (63 - s) : s;
    const int rm = t_in & 15, tq = t_in >> 4;
    const int eoff = ((rm >> 2) * 16 + ln) * 4 + (rm & 3);
#pragma unroll
    for (int i = 0; i < 2; ++i) {
      const int mtile_i = mtr0 + i;
#pragma unroll
      for (int r = 0; r < 4; ++r) {
        const int b = mtile_i * 16 + lq * 4 + r;  // batch index (C/D row)
        const long gmt = (long)b * 4 + tq;        // gx/x1 row-tile = (b*64+t)>>4
        const float xr = (float)gx[(gmt * 192 + ntg0) * 256 + eoff];
        const float xz = (float)gx[(gmt * 192 + ntg0 + 32) * 256 + eoff];
        const float xn = (float)gx[(gmt * 192 + ntg0 + 64) * 256 + eoff];
        const float rg = sigm_f(xr + acc[0][i][r] + bh0);
        const float zg = sigm_f(xz + acc[1][i][r] + bh1);
        const float ng = tanh_f(xn + rg * (acc[2][i][r] + bh2));
        const float hv = (1.f - zg) * ng + zg * hreg[i][r];
        hreg[i][r] = hv;
        // h for next step (frag layout)
        hwr[((long)mtile_i * 16 + ksh) * 512 + (qh * 16 + lq * 4 + r) * 8 + jh] = (_Float16)hv;
        if (ys != nullptr) {  // layer-0: emit x1 in frag layout (KI=32)
          const int kcol = d * 512 + hcol;
          ys[(gmt * 32 + (kcol >> 5)) * 512 + (((kcol >> 3) & 3) * 16 + rm) * 8 + (kcol & 7)] =
              (_Float16)hv;
        }
        if (last != nullptr && ((d == 0 && s == 63) || (d == 1 && s == 0)))
          last[(long)b * 1024 + d * 512 + hcol] = hv;  // h2[:, t=63, :]
      }
    }
    // group barrier: syncthreads drains all waves' stores to L2 (vmcnt0),
    // release RMW writes back XCD L2, relaxed poll, acquire fence invalidates.
    __syncthreads();
    if (tid == 0) {
      __hip_atomic_fetch_add(gc, 1u, __ATOMIC_RELEASE, __HIP_MEMORY_SCOPE_AGENT);
      const unsigned int tgt = 16u * (unsigned int)(s + 1);
      long guard = 0;
      while (__hip_atomic_load(gc, __ATOMIC_RELAXED, __HIP_MEMORY_SCOPE_AGENT) < tgt) {
        __builtin_amdgcn_s_sleep(2);
        if (++guard > (1L << 22)) break;  // bail out instead of hanging forever
      }
      __builtin_amdgcn_fence(__ATOMIC_ACQUIRE, "agent");
    }
    __syncthreads();
  }
}

// out[b][o] = last[b] . fc_w[o] + fc_b[o];  512 blocks x 1 wave
__global__ void fc_kernel(const float* __restrict__ lastb, const float* __restrict__ fw,
                          const float* __restrict__ fb, float* __restrict__ out) {
  const int b = blockIdx.x, l = threadIdx.x;
  const float* x = lastb + (long)b * 1024;
  float a0 = 0.f, a1 = 0.f;
  for (int k = l; k < 1024; k += 64) {
    const float v = x[k];
    a0 += v * fw[k];
    a1 += v * fw[1024 + k];
  }
#pragma unroll
  for (int off = 32; off > 0; off >>= 1) {
    a0 += __shfl_down(a0, off, 64);
    a1 += __shfl_down(a1, off, 64);
  }
  if (l == 0) {
    out[b * 2 + 0] = a0 + fb[0];
    out[b * 2 + 1] = a1 + fb[1];
  }
}

extern "C" void kernel_launch(void* const* d_in, const int* in_sizes, int n_in,
                              void* d_out, int out_size, void* d_ws, size_t ws_size,
                              hipStream_t stream) {
  const int* tokens = (const int*)d_in[0];
  const float* emb = (const float*)d_in[1];
  const float* w_ih0 = (const float*)d_in[2];
  const float* w_hh0 = (const float*)d_in[3];
  const float* b_ih0 = (const float*)d_in[4];
  const float* b_hh0 = (const float*)d_in[5];
  const float* w_ih1 = (const float*)d_in[6];
  const float* w_hh1 = (const float*)d_in[7];
  const float* b_ih1 = (const float*)d_in[8];
  const float* b_hh1 = (const float*)d_in[9];
  const float* fc_w = (const float*)d_in[10];
  const float* fc_b = (const float*)d_in[11];
  float* out = (float*)d_out;

  char* ws = (char*)d_ws;
  size_t off = 0;
  auto alloc = [&](size_t bytes) -> void* {
    void* p = ws + off;
    off += (bytes + 255) & ~(size_t)255;
    return p;
  };
  _Float16* W0f = (_Float16*)alloc(192L * 10 * 512 * 2);   // w_ih0 frags (K 300->320)
  _Float16* W1f = (_Float16*)alloc(192L * 32 * 512 * 2);   // w_ih1 frags (K=1024)
  _Float16* Wh0f = (_Float16*)alloc(192L * 16 * 512 * 2);  // w_hh0 frags
  _Float16* Wh1f = (_Float16*)alloc(192L * 16 * 512 * 2);  // w_hh1 frags
  _Float16* x0f = (_Float16*)alloc(2048L * 10 * 512 * 2);  // embedded input frags
  _Float16* x1f = (_Float16*)alloc(2048L * 32 * 512 * 2);  // layer-0 output frags
  _Float16* gxb = (_Float16*)alloc(2048L * 192 * 256 * 2); // gx (shared L0/L1)
  char* hz = ws + off;                                     // memset region start
  _Float16* hbuf = (_Float16*)alloc(4L * 32 * 8192 * 2);   // h double-buffer, 2 dirs
  unsigned int* cnt = (unsigned int*)alloc(4096);          // group barrier counters
  const size_t hz_bytes = 4L * 32 * 8192 * 2 + 4096;
  float* lastb = (float*)alloc(512L * 1024 * 4);
  if (off > ws_size) return;  // workspace too small -> visible absmax failure

  pack_b_kernel<<<dim3(192 * 10 * 64 / 256), 256, 0, stream>>>(w_ih0, W0f, 300, 10);
  pack_b_kernel<<<dim3(192 * 32 * 64 / 256), 256, 0, stream>>>(w_ih1, W1f, 1024, 32);
  pack_b_kernel<<<dim3(192 * 16 * 64 / 256), 256, 0, stream>>>(w_hh0, Wh0f, 512, 16);
  pack_b_kernel<<<dim3(192 * 16 * 64 / 256), 256, 0, stream>>>(w_hh1, Wh1f, 512, 16);
  gather_kernel<<<dim3(2048 * 10 * 64 / 256), 256, 0, stream>>>(tokens, emb, x0f);

  gemm_bt_kernel<<<dim3(24, 256), 256, 0, stream>>>(x0f, W0f, b_ih0, gxb, 10);
  hipMemsetAsync(hz, 0, hz_bytes, stream);
  gru_scan_kernel<<<dim3(256), 256, 0, stream>>>(Wh0f, b_hh0, gxb, hbuf, x1f, nullptr, cnt);

  gemm_bt_kernel<<<dim3(24, 256), 256, 0, stream>>>(x1f, W1f, b_ih1, gxb, 32);
  hipMemsetAsync(hz, 0, hz_bytes, stream);
  gru_scan_kernel<<<dim3(256), 256, 0, stream>>>(Wh1f, b_hh1, gxb, hbuf, nullptr, lastb, cnt);

  fc_kernel<<<dim3(512), 64, 0, stream>>>(lastb, fc_w, fc_b, out);
}

// Round 2
// 1501.525 us; speedup vs baseline: 2.0152x; 2.0152x over previous
//
#include <hip/hip_runtime.h>
#include <stdint.h>

// ============================================================================
// GRU_Model: 2-layer bidirectional GRU, B=512 T=64 E=300 H=512, fp16 MFMA.
//
// Frag layouts as in round 0. Round-1 change: the scan's cross-block h
// exchange uses relaxed AGENT-scope atomics (sc1 -> MALL-coherent, bypass
// L1/L2) instead of release/acquire fences. No buffer_wbl2/buffer_inv per
// step => gx/whh stay L2-cached, barrier is ~1 us instead of ~15 us.
// ============================================================================

#define NTW 192   // 3072/16 gate-column tiles (both dirs)
#define MTX 2048  // 32768/16 row tiles (B*T)

typedef _Float16 half8 __attribute__((ext_vector_type(8)));
typedef _Float16 half4_t __attribute__((ext_vector_type(4)));
typedef float float4_t __attribute__((ext_vector_type(4)));

__device__ __forceinline__ void gl_lds16(const void* g, void* l) {
  __builtin_amdgcn_global_load_lds(
      (const __attribute__((address_space(1))) void*)g,
      (__attribute__((address_space(3))) void*)l, 16, 0, 0);
}

__device__ __forceinline__ float sigm_f(float x) { return 1.f / (1.f + __expf(-x)); }
__device__ __forceinline__ float tanh_f(float x) { return 1.f - 2.f / (__expf(2.f * x) + 1.f); }

// f32 (3072, K) row-major -> fp16 frag layout [192][KI][64][8], zero-pad to KI*32
__global__ void pack_b_kernel(const float* __restrict__ src, _Float16* __restrict__ dst,
                              int K, int KI) {
  int gid = blockIdx.x * 256 + threadIdx.x;
  int l = gid & 63, unit = gid >> 6;
  int nt = unit / KI, ks = unit - nt * KI;
  if (nt >= NTW) return;
  int row = nt * 16 + (l & 15);
  int col0 = ks * 32 + ((l >> 4) << 3);
  half8 v;
#pragma unroll
  for (int j = 0; j < 8; ++j) {
    int c = col0 + j;
    v[j] = (c < K) ? (_Float16)src[(long)row * K + c] : (_Float16)0.f;
  }
  *(half8*)(dst + (long)unit * 512 + l * 8) = v;
}

// embedding gather -> x0 frag layout [2048][10][64][8] (K=300 padded to 320)
__global__ void gather_kernel(const int* __restrict__ tokens, const float* __restrict__ emb,
                              _Float16* __restrict__ x0) {
  int gid = blockIdx.x * 256 + threadIdx.x;
  int l = gid & 63, unit = gid >> 6;
  int mt = unit / 10, ks = unit - mt * 10;
  if (mt >= MTX) return;
  int row = mt * 16 + (l & 15);  // row = b*64 + t
  const float* e = emb + (long)tokens[row] * 300;
  int col0 = ks * 32 + ((l >> 4) << 3);
  half8 v;
#pragma unroll
  for (int j = 0; j < 8; ++j) {
    int c = col0 + j;
    v[j] = (c < 300) ? (_Float16)e[c] : (_Float16)0.f;
  }
  *(half8*)(x0 + (long)unit * 512 + l * 8) = v;
}

// C(M=32768,N=3072) = A(M,K) * B(N,K)^T + bias[n];  A,B frag-layout fp16,
// C in C-frag tile layout [mtile][ntile][256] fp16.  grid (24, 256), 256 thr.
__global__ __launch_bounds__(256) void gemm_bt_kernel(
    const _Float16* __restrict__ A, const _Float16* __restrict__ Bw,
    const float* __restrict__ bias, _Float16* __restrict__ C, int KI) {
  __shared__ _Float16 As[8 * 512];
  __shared__ _Float16 Bs[8 * 512];
  const int bx = blockIdx.x, by = blockIdx.y;
  const int tid = threadIdx.x, w = tid >> 6, l = tid & 63;
  const int wm = w >> 1, wn = w & 1, ln = l & 15;
  const int mt0 = by * 8, nt0 = bx * 8;
  float4_t acc[4][4];
#pragma unroll
  for (int i = 0; i < 4; ++i)
#pragma unroll
    for (int j = 0; j < 4; ++j) acc[i][j] = 0.f;
  for (int it = 0; it < KI; ++it) {
    __syncthreads();  // protect LDS from previous iter's readers
    gl_lds16(A + ((long)(mt0 + w) * KI + it) * 512 + l * 8, As + w * 512 + l * 8);
    gl_lds16(A + ((long)(mt0 + w + 4) * KI + it) * 512 + l * 8, As + (w + 4) * 512 + l * 8);
    gl_lds16(Bw + ((long)(nt0 + w) * KI + it) * 512 + l * 8, Bs + w * 512 + l * 8);
    gl_lds16(Bw + ((long)(nt0 + w + 4) * KI + it) * 512 + l * 8, Bs + (w + 4) * 512 + l * 8);
    __syncthreads();  // compiler emits vmcnt(0) drain
    half8 af[4], bf[4];
#pragma unroll
    for (int i = 0; i < 4; ++i) af[i] = *(const half8*)(As + (wm * 4 + i) * 512 + l * 8);
#pragma unroll
    for (int j = 0; j < 4; ++j) bf[j] = *(const half8*)(Bs + (wn * 4 + j) * 512 + l * 8);
#pragma unroll
    for (int i = 0; i < 4; ++i)
#pragma unroll
      for (int j = 0; j < 4; ++j)
        acc[i][j] = __builtin_amdgcn_mfma_f32_16x16x32_f16(af[i], bf[j], acc[i][j], 0, 0, 0);
  }
#pragma unroll
  for (int i = 0; i < 4; ++i)
#pragma unroll
    for (int j = 0; j < 4; ++j) {
      int mt = mt0 + wm * 4 + i, ntile = nt0 + wn * 4 + j;
      float bv = bias[ntile * 16 + ln];
      half4_t o;
#pragma unroll
      for (int r = 0; r < 4; ++r) o[r] = (_Float16)(acc[i][j][r] + bv);
      *(half4_t*)(C + ((long)mt * NTW + ntile) * 256 + l * 4) = o;  // coalesced 8B
    }
}

// Persistent bidirectional GRU scan over 64 steps.
// grid 256 = d(2) x mtb(8: 64 batch rows) x nt(16: 32 h-cols). 256 thr.
// hbuf: [d*2+parity][512 units][512 halves] fp16 frag layout (512KB/slot).
// All hbuf accesses + group counter: relaxed agent-scope atomics (sc1).
__global__ __launch_bounds__(256, 1) void gru_scan_kernel(
    const _Float16* __restrict__ whh,  // [192][16][64][8]
    const float* __restrict__ bhh,     // [3072]
    const _Float16* __restrict__ gx,   // [2048][192][256] (C-frag tiles)
    _Float16* hbuf, _Float16* ys,      // ys: x1 frag [2048][32][64][8] or null
    float* last,                       // [512][1024] f32 or null
    unsigned int* cnt) {               // 16 group counters, 128B stride
  __shared__ alignas(16) _Float16 hx[4 * 512];  // 4KB h transpose buffer
  const int bid = blockIdx.x;
  const int d = bid >> 7, mtb = (bid >> 4) & 7, nt = bid & 15;
  const int tid = threadIdx.x, w = tid >> 6, l = tid & 63;
  const int wm = w >> 1, wn = w & 1, lq = l >> 4, ln = l & 15;
  unsigned int* gc = cnt + (d * 8 + mtb) * 32;
  const int hcol = nt * 32 + wn * 16 + ln;  // this lane's h column

  // Whh slice resident in VGPRs for all 64 steps (48 frags = 192 VGPRs)
  half8 bf[3][16];
#pragma unroll
  for (int g = 0; g < 3; ++g) {
    const int tg = d * 96 + g * 32 + nt * 2 + wn;
#pragma unroll
    for (int ks = 0; ks < 16; ++ks)
      bf[g][ks] = *(const half8*)(whh + (long)(tg * 16 + ks) * 512 + l * 8);
  }
  const float bh0 = bhh[d * 1536 + hcol];
  const float bh1 = bhh[d * 1536 + 512 + hcol];
  const float bh2 = bhh[d * 1536 + 1024 + hcol];
  float hreg[2][4] = {{0.f, 0.f, 0.f, 0.f}, {0.f, 0.f, 0.f, 0.f}};  // fp32 master h
  const int mtr0 = mtb * 4 + wm * 2;  // global h row-tile for i=0
  const int qh = (hcol >> 3) & 3, jh = hcol & 7;
  const int ntg0 = d * 96 + nt * 2 + wn;
  const unsigned long long* hb8 = (const unsigned long long*)hbuf;

  for (int s = 0; s < 64; ++s) {
    const int par = s & 1;
    const unsigned long long* hr8 = hb8 + (long)(d * 2 + par) * 65536;
    const int t_in = d ? (63 - s) : s;
    const int rm = t_in & 15, tq = t_in >> 4;
    const int eoff = ((rm >> 2) * 16 + ln) * 4 + (rm & 3);

    // issue gx loads early (normal cached loads; L2 stays warm — no inv)
    float xr[2][4], xz[2][4], xn[2][4];
#pragma unroll
    for (int i = 0; i < 2; ++i)
#pragma unroll
      for (int r = 0; r < 4; ++r) {
        const int b = (mtr0 + i) * 16 + lq * 4 + r;
        const long gbase = ((long)(b * 4 + tq) * 192 + ntg0) * 256 + eoff;
        xr[i][r] = (float)gx[gbase];
        xz[i][r] = (float)gx[gbase + 32 * 256];
        xn[i][r] = (float)gx[gbase + 64 * 256];
      }

    float4_t acc[3][2];
#pragma unroll
    for (int g = 0; g < 3; ++g) { acc[g][0] = 0.f; acc[g][1] = 0.f; }
#pragma unroll
    for (int kk = 0; kk < 2; ++kk) {  // 2 chunks of 8 k-steps caps af VGPRs
      half8 af[2][8];
#pragma unroll
      for (int i = 0; i < 2; ++i)
#pragma unroll
        for (int k2 = 0; k2 < 8; ++k2) {
          const unsigned long long* p =
              hr8 + ((long)(mtr0 + i) * 16 + kk * 8 + k2) * 128 + l * 2;
          union { half8 h; unsigned long long q[2]; } fu;
          fu.q[0] = __hip_atomic_load(p, __ATOMIC_RELAXED, __HIP_MEMORY_SCOPE_AGENT);
          fu.q[1] = __hip_atomic_load(p + 1, __ATOMIC_RELAXED, __HIP_MEMORY_SCOPE_AGENT);
          af[i][k2] = fu.h;
        }
#pragma unroll
      for (int k2 = 0; k2 < 8; ++k2)
#pragma unroll
        for (int i = 0; i < 2; ++i)
#pragma unroll
          for (int g = 0; g < 3; ++g)
            acc[g][i] = __builtin_amdgcn_mfma_f32_16x16x32_f16(af[i][k2], bf[g][kk * 8 + k2],
                                                               acc[g][i], 0, 0, 0);
    }

#pragma unroll
    for (int i = 0; i < 2; ++i) {
      const int mtile_i = mtr0 + i;
#pragma unroll
      for (int r = 0; r < 4; ++r) {
        const int b = mtile_i * 16 + lq * 4 + r;  // batch index (C/D row)
        const long gmt = (long)b * 4 + tq;        // gx/x1 row-tile = (b*64+t)>>4
        const float rg = sigm_f(xr[i][r] + acc[0][i][r] + bh0);
        const float zg = sigm_f(xz[i][r] + acc[1][i][r] + bh1);
        const float ng = tanh_f(xn[i][r] + rg * (acc[2][i][r] + bh2));
        const float hv = (1.f - zg) * ng + zg * hreg[i][r];
        hreg[i][r] = hv;
        // stage h for next step into LDS (transpose to contiguous 16B/thread)
        hx[(wm * 2 + i) * 512 + (qh * 16 + lq * 4 + r) * 8 + jh] = (_Float16)hv;
        if (ys != nullptr) {  // layer-0: emit x1 in frag layout (KI=32)
          const int kcol = d * 512 + hcol;
          ys[(gmt * 32 + (kcol >> 5)) * 512 + (((kcol >> 3) & 3) * 16 + rm) * 8 + (kcol & 7)] =
              (_Float16)hv;
        }
        if (last != nullptr && ((d == 0 && s == 63) || (d == 1 && s == 0)))
          last[(long)b * 1024 + d * 512 + hcol] = hv;  // h2[:, t=63, :]
      }
    }
    if (s == 63) break;  // last h never consumed

    __syncthreads();  // LDS transpose complete
    {                 // 16B/thread from LDS -> two 8B sc1 stores (MALL-coherent)
      const int u = tid >> 6, lw = tid & 63;
      union { half8 h; unsigned long long q[2]; } wb;
      wb.h = *(const half8*)(hx + u * 512 + lw * 8);
      unsigned long long* dst = (unsigned long long*)hbuf +
                                (long)(d * 2 + (par ^ 1)) * 65536 +
                                ((long)((mtb * 4 + u) * 16 + nt)) * 128 + lw * 2;
      __hip_atomic_store(dst, wb.q[0], __ATOMIC_RELAXED, __HIP_MEMORY_SCOPE_AGENT);
      __hip_atomic_store(dst + 1, wb.q[1], __ATOMIC_RELAXED, __HIP_MEMORY_SCOPE_AGENT);
    }
    __syncthreads();  // per-wave vmcnt(0) drain => all sc1 stores at MALL
    if (tid == 0) {   // group barrier: relaxed RMW + relaxed poll, NO agent fences
      __hip_atomic_fetch_add(gc, 1u, __ATOMIC_RELAXED, __HIP_MEMORY_SCOPE_AGENT);
      const unsigned int tgt = 16u * (unsigned int)(s + 1);
      long guard = 0;
      while (__hip_atomic_load(gc, __ATOMIC_RELAXED, __HIP_MEMORY_SCOPE_AGENT) < tgt) {
        __builtin_amdgcn_s_sleep(1);
        if (++guard > (1L << 24)) break;  // bail out instead of hanging forever
      }
      __builtin_amdgcn_fence(__ATOMIC_ACQUIRE, "workgroup");  // cheap: no cache ops
    }
    __syncthreads();
  }
}

// out[b][o] = last[b] . fc_w[o] + fc_b[o];  512 blocks x 1 wave
__global__ void fc_kernel(const float* __restrict__ lastb, const float* __restrict__ fw,
                          const float* __restrict__ fb, float* __restrict__ out) {
  const int b = blockIdx.x, l = threadIdx.x;
  const float* x = lastb + (long)b * 1024;
  float a0 = 0.f, a1 = 0.f;
  for (int k = l; k < 1024; k += 64) {
    const float v = x[k];
    a0 += v * fw[k];
    a1 += v * fw[1024 + k];
  }
#pragma unroll
  for (int off = 32; off > 0; off >>= 1) {
    a0 += __shfl_down(a0, off, 64);
    a1 += __shfl_down(a1, off, 64);
  }
  if (l == 0) {
    out[b * 2 + 0] = a0 + fb[0];
    out[b * 2 + 1] = a1 + fb[1];
  }
}

extern "C" void kernel_launch(void* const* d_in, const int* in_sizes, int n_in,
                              void* d_out, int out_size, void* d_ws, size_t ws_size,
                              hipStream_t stream) {
  const int* tokens = (const int*)d_in[0];
  const float* emb = (const float*)d_in[1];
  const float* w_ih0 = (const float*)d_in[2];
  const float* w_hh0 = (const float*)d_in[3];
  const float* b_ih0 = (const float*)d_in[4];
  const float* b_hh0 = (const float*)d_in[5];
  const float* w_ih1 = (const float*)d_in[6];
  const float* w_hh1 = (const float*)d_in[7];
  const float* b_ih1 = (const float*)d_in[8];
  const float* b_hh1 = (const float*)d_in[9];
  const float* fc_w = (const float*)d_in[10];
  const float* fc_b = (const float*)d_in[11];
  float* out = (float*)d_out;

  char* ws = (char*)d_ws;
  size_t off = 0;
  auto alloc = [&](size_t bytes) -> void* {
    void* p = ws + off;
    off += (bytes + 255) & ~(size_t)255;
    return p;
  };
  _Float16* W0f = (_Float16*)alloc(192L * 10 * 512 * 2);   // w_ih0 frags (K 300->320)
  _Float16* W1f = (_Float16*)alloc(192L * 32 * 512 * 2);   // w_ih1 frags (K=1024)
  _Float16* Wh0f = (_Float16*)alloc(192L * 16 * 512 * 2);  // w_hh0 frags
  _Float16* Wh1f = (_Float16*)alloc(192L * 16 * 512 * 2);  // w_hh1 frags
  _Float16* x0f = (_Float16*)alloc(2048L * 10 * 512 * 2);  // embedded input frags
  _Float16* x1f = (_Float16*)alloc(2048L * 32 * 512 * 2);  // layer-0 output frags
  _Float16* gxb = (_Float16*)alloc(2048L * 192 * 256 * 2); // gx (shared L0/L1)
  char* hz = ws + off;                                     // memset region start
  _Float16* hbuf = (_Float16*)alloc(4L * 32 * 8192 * 2);   // h double-buffer, 2 dirs
  unsigned int* cnt = (unsigned int*)alloc(4096);          // group barrier counters
  const size_t hz_bytes = 4L * 32 * 8192 * 2 + 4096;
  float* lastb = (float*)alloc(512L * 1024 * 4);
  if (off > ws_size) return;  // workspace too small -> visible absmax failure

  pack_b_kernel<<<dim3(192 * 10 * 64 / 256), 256, 0, stream>>>(w_ih0, W0f, 300, 10);
  pack_b_kernel<<<dim3(192 * 32 * 64 / 256), 256, 0, stream>>>(w_ih1, W1f, 1024, 32);
  pack_b_kernel<<<dim3(192 * 16 * 64 / 256), 256, 0, stream>>>(w_hh0, Wh0f, 512, 16);
  pack_b_kernel<<<dim3(192 * 16 * 64 / 256), 256, 0, stream>>>(w_hh1, Wh1f, 512, 16);
  gather_kernel<<<dim3(2048 * 10 * 64 / 256), 256, 0, stream>>>(tokens, emb, x0f);

  gemm_bt_kernel<<<dim3(24, 256), 256, 0, stream>>>(x0f, W0f, b_ih0, gxb, 10);
  hipMemsetAsync(hz, 0, hz_bytes, stream);
  gru_scan_kernel<<<dim3(256), 256, 0, stream>>>(Wh0f, b_hh0, gxb, hbuf, x1f, nullptr, cnt);

  gemm_bt_kernel<<<dim3(24, 256), 256, 0, stream>>>(x1f, W1f, b_ih1, gxb, 32);
  hipMemsetAsync(hz, 0, hz_bytes, stream);
  gru_scan_kernel<<<dim3(256), 256, 0, stream>>>(Wh1f, b_hh1, gxb, hbuf, nullptr, lastb, cnt);

  fc_kernel<<<dim3(512), 64, 0, stream>>>(lastb, fc_w, fc_b, out);
}